// Round 8
// baseline (270.951 us; speedup 1.0000x reference)
//
#include <hip/hip_runtime.h>

// Problem constants
#define BB      16384
#define IN_DIM  256
#define NE      32
#define H1D     64
#define H2D     256
#define H3D     128
#define NOUT    128

typedef __bf16 bf16_t;
typedef __bf16 bf16x4_t __attribute__((ext_vector_type(4)));
typedef __bf16 bf16x8  __attribute__((ext_vector_type(8)));
typedef float  f32x4   __attribute__((ext_vector_type(4)));
typedef float  f32x16  __attribute__((ext_vector_type(16)));

// ---- workspace: fragment-ordered bf16 weights ----
// Per expert, 160 "sets" of 64 lanes x 16B, contiguous in set order:
//   sets [0,32):    L1  16x16 (tile 0..3,  ks 0..7)   K=256, N=64
//   sets [32,64):   L2  32x32 (tile 0..7,  ks 0..3)   K=64,  N=256
//   sets [64,128):  L3  32x32 (tile 0..3,  ks 0..15)  K=256, N=128
//   sets [128,144): L4  16x16 (tile 0..3,  ks 0..3)   K=128, N=64
//   sets [144,160): L5  32x32 (tile 0..3,  ks 0..3)   K=64,  N=128
// 16x16 frag: dst[..+j] = W[ks*32+(l>>4)*8+j][t*16+(l&15)]
// 32x32 frag: dst[..+j] = W[ks*16+(l>>5)*8+j][t*32+(l&31)]
#define OFF_WF   ((size_t)0)
#define OFF_WGF  ((size_t)NE * 81920 * 2)     // Wg frags: 16 sets (16x16) = 16 KB

// ---- prep: one thread per fragment ----
__global__ __launch_bounds__(256) void build_frags(
    const float* __restrict__ W1, const float* __restrict__ W2,
    const float* __restrict__ W3, const float* __restrict__ W4,
    const float* __restrict__ W5, const float* __restrict__ Wg,
    bf16_t* __restrict__ Wf, bf16_t* __restrict__ Wgf)
{
    const int g    = blockIdx.x * 256 + threadIdx.x;
    const int lane = g & 63;
    const int set  = g >> 6;            // 0 .. 5135
    const float* src; bf16_t* dst; int N, t, ks; bool big;
    if (set < 5120) {
        const int e = set / 160;
        const int s = set % 160;
        dst = Wf + (size_t)e * 81920 + ((size_t)s * 64 + lane) * 8;
        if (s < 32)       { t = s >> 3;            ks = s & 7;          N = 64;  big = false; src = W1 + (size_t)e * 16384; }
        else if (s < 64)  { int r = s - 32;  t = r >> 2;  ks = r & 3;   N = 256; big = true;  src = W2 + (size_t)e * 16384; }
        else if (s < 128) { int r = s - 64;  t = r >> 4;  ks = r & 15;  N = 128; big = true;  src = W3 + (size_t)e * 32768; }
        else if (s < 144) { int r = s - 128; t = r >> 2;  ks = r & 3;   N = 64;  big = false; src = W4 + (size_t)e * 8192;  }
        else              { int r = s - 144; t = r >> 2;  ks = r & 3;   N = 128; big = true;  src = W5 + (size_t)e * 8192;  }
    } else {
        const int s = set - 5120;
        t = s >> 3; ks = s & 7; N = 32; big = false; src = Wg;
        dst = Wgf + ((size_t)s * 64 + lane) * 8;
    }
    int f, k0;
    if (big) { f = t * 32 + (lane & 31); k0 = ks * 16 + (lane >> 5) * 8; }
    else     { f = t * 16 + (lane & 15); k0 = ks * 32 + (lane >> 4) * 8; }
    bf16x8 o;
#pragma unroll
    for (int j = 0; j < 8; j++) o[j] = (bf16_t)src[(size_t)(k0 + j) * N + f];
    *(bf16x8*)dst = o;
}

// ---- swizzled LDS addressing: 16B-granule XOR with row&7 (bank-balanced) ----
template<int RS>
__device__ __forceinline__ void* swzp(char* base, int row, int byteoff) {
    const int g = byteoff >> 4;
    return (void*)(base + ((row << RS) | ((g ^ (row & 7)) << 4) | (byteoff & 15)));
}

// ---- LDS carve: 64-row tile ----
#define L_H1   0          // h1 [64][128B]  RS=7   8 KB
#define L_SX   8192       // x  [64][512B]  RS=9  32 KB
#define L_H2   40960      // h2 [64][512B]  RS=9  32 KB
#define L_H3   73728      // h3 [64][256B]  RS=8  16 KB (alias gating logits [64][36] f32)
#define L_H4   90112      // h4 [64][128B]  RS=7   8 KB
#define L_SG   98304      // g  [32e][64b] f32     8 KB
#define L_TOT  106496

// ---- main: 64-row tile, 8 waves, 256 blocks; 2 barriers/expert,
//      one-phase-ahead prefetch; L2/L3/L5 on 32x32x16; wC split to kill spills ----
__global__ __launch_bounds__(512) void moe_main(
    const float* __restrict__ x, const bf16_t* __restrict__ Wf,
    const bf16_t* __restrict__ Wgf, const float* __restrict__ bg,
    const float* __restrict__ b1, const float* __restrict__ b2,
    const float* __restrict__ b3, const float* __restrict__ b4,
    const float* __restrict__ b5, float* __restrict__ out)
{
    __shared__ __align__(16) char lds[L_TOT];
    char* sX = lds + L_SX;
    char* h1 = lds + L_H1;
    char* h2 = lds + L_H2;
    char* h3 = lds + L_H3;
    char* h4 = lds + L_H4;
    float* sG = (float*)(lds + L_SG);

    const int tid  = threadIdx.x;
    const int w    = tid >> 6;
    const int lane = tid & 63;
    const int c    = lane & 15;          // 16x16 lane mapping
    const int q    = lane >> 4;
    const int c2   = lane & 31;          // 32x32 lane mapping
    const int h    = lane >> 5;
    const int fg   = w & 3;              // f-tile index (all layers)
    const int mh   = w >> 2;             // m-half
    const int bb   = mh * 32 + c2;       // batch row for 32x32 layers
    const int b0   = blockIdx.x * 64;

    bf16x8 wA[8], wB[2][4], wCa[8], wCb[8], wD[4], wE[4];

    // early issue: wA(0) [L1 tile fg], wB(0) [L2 tiles fg*2..+1]
#pragma unroll
    for (int ks = 0; ks < 8; ks++)
        wA[ks] = *(const bf16x8*)(Wf + ((size_t)(fg * 8 + ks) * 64 + lane) * 8);
#pragma unroll
    for (int jt = 0; jt < 2; jt++)
#pragma unroll
        for (int ks = 0; ks < 4; ks++)
            wB[jt][ks] = *(const bf16x8*)(Wf + ((size_t)(32 + (fg * 2 + jt) * 4 + ks) * 64 + lane) * 8);

    // ---- stage x: 64x256 fp32 -> bf16, swizzled ----
    {
        const int r  = tid >> 3;
        const int c0 = (tid & 7) * 32;
        const float* sp = x + (size_t)(b0 + r) * IN_DIM + c0;
#pragma unroll
        for (int jj = 0; jj < 4; jj++) {
            const float4 v0 = *(const float4*)(sp + jj * 8);
            const float4 v1 = *(const float4*)(sp + jj * 8 + 4);
            bf16x8 o = { (bf16_t)v0.x, (bf16_t)v0.y, (bf16_t)v0.z, (bf16_t)v0.w,
                         (bf16_t)v1.x, (bf16_t)v1.y, (bf16_t)v1.z, (bf16_t)v1.w };
            *(bf16x8*)swzp<9>(sX, r, c0 * 2 + jj * 16) = o;
        }
    }
    __syncthreads();

    // ---- gating logits -> h3 alias [64][36] f32 (16x16) ----
    {
        const int t = w & 1, m = w >> 1;
        f32x4 acc = (f32x4){0.f, 0.f, 0.f, 0.f};
#pragma unroll
        for (int ks = 0; ks < 8; ks++) {
            bf16x8 xv = *(const bf16x8*)swzp<9>(sX, m * 16 + c, ks * 64 + q * 16);
            bf16x8 wg = *(const bf16x8*)(Wgf + ((size_t)(t * 8 + ks) * 64 + lane) * 8);
            acc = __builtin_amdgcn_mfma_f32_16x16x32_bf16(wg, xv, acc, 0, 0, 0);
        }
        const float4 bgv = *(const float4*)(bg + t * 16 + q * 4);
        float* sLgF = (float*)h3;
        *(float4*)(sLgF + (size_t)(m * 16 + c) * 36 + t * 16 + q * 4) =
            (float4){acc[0] + bgv.x, acc[1] + bgv.y, acc[2] + bgv.z, acc[3] + bgv.w};
    }
    __syncthreads();

    // ---- softmax -> sG ; L1(0): sX -> h1 ----
    {
        const int r = tid >> 3;
        const int j = tid & 7;
        const float* sLgF = (const float*)h3;
        float4 l = *(const float4*)(sLgF + (size_t)r * 36 + j * 4);
        float mx = fmaxf(fmaxf(l.x, l.y), fmaxf(l.z, l.w));
#pragma unroll
        for (int off = 1; off < 8; off <<= 1) mx = fmaxf(mx, __shfl_xor(mx, off));
        float e0 = __expf(l.x - mx), e1 = __expf(l.y - mx),
              e2 = __expf(l.z - mx), e3 = __expf(l.w - mx);
        float sm = e0 + e1 + e2 + e3;
#pragma unroll
        for (int off = 1; off < 8; off <<= 1) sm += __shfl_xor(sm, off);
        const float rs = 1.f / sm;
        sG[(j * 4 + 0) * 64 + r] = e0 * rs;
        sG[(j * 4 + 1) * 64 + r] = e1 * rs;
        sG[(j * 4 + 2) * 64 + r] = e2 * rs;
        sG[(j * 4 + 3) * 64 + r] = e3 * rs;
    }
    {
        const float4 bv = *(const float4*)(b1 + fg * 16 + q * 4);
#pragma unroll
        for (int mm = 0; mm < 2; mm++) {
            const int m = mh * 2 + mm;
            f32x4 acc = (f32x4){0.f, 0.f, 0.f, 0.f};
#pragma unroll
            for (int ks = 0; ks < 8; ks++) {
                bf16x8 xv = *(const bf16x8*)swzp<9>(sX, m * 16 + c, ks * 64 + q * 16);
                acc = __builtin_amdgcn_mfma_f32_16x16x32_bf16(wA[ks], xv, acc, 0, 0, 0);
            }
            bf16x4_t hv = { (bf16_t)fmaxf(acc[0] + bv.x, 0.f),
                            (bf16_t)fmaxf(acc[1] + bv.y, 0.f),
                            (bf16_t)fmaxf(acc[2] + bv.z, 0.f),
                            (bf16_t)fmaxf(acc[3] + bv.w, 0.f) };
            *(bf16x4_t*)swzp<7>(h1, m * 16 + c, fg * 32 + q * 8) = hv;
        }
    }
    __syncthreads();

    float oacc[16];
#pragma unroll
    for (int r = 0; r < 16; r++) oacc[r] = 0.f;

    auto do_l5 = [&](int ep) {   // 32x32: h4 -> oacc, f-tile fg, m-half mh (wE prefetched)
        f32x16 p;
#pragma unroll
        for (int r = 0; r < 16; r++) p[r] = 0.f;
#pragma unroll
        for (int ks = 0; ks < 4; ks++) {
            bf16x8 ha = *(const bf16x8*)swzp<7>(h4, bb, ks * 32 + h * 16);
            p = __builtin_amdgcn_mfma_f32_32x32x16_bf16(wE[ks], ha, p, 0, 0, 0);
        }
        const float gv = sG[ep * 64 + bb];
#pragma unroll
        for (int t = 0; t < 4; t++) {
            const float4 bv = *(const float4*)(b5 + (size_t)ep * NOUT + fg * 32 + t * 8 + h * 4);
            oacc[4 * t + 0] += gv * (p[4 * t + 0] + bv.x);
            oacc[4 * t + 1] += gv * (p[4 * t + 1] + bv.y);
            oacc[4 * t + 2] += gv * (p[4 * t + 2] + bv.z);
            oacc[4 * t + 3] += gv * (p[4 * t + 3] + bv.w);
        }
    };

    auto do_l4 = [&](int ep) {   // 16x16: h3 -> h4, f-tile fg, rows mh half (wD prefetched)
        const float4 bv = *(const float4*)(b4 + (size_t)ep * H1D + fg * 16 + q * 4);
#pragma unroll
        for (int mm = 0; mm < 2; mm++) {
            const int m = mh * 2 + mm;
            f32x4 acc = (f32x4){0.f, 0.f, 0.f, 0.f};
#pragma unroll
            for (int ks = 0; ks < 4; ks++) {
                bf16x8 ha = *(const bf16x8*)swzp<8>(h3, m * 16 + c, ks * 64 + q * 16);
                acc = __builtin_amdgcn_mfma_f32_16x16x32_bf16(wD[ks], ha, acc, 0, 0, 0);
            }
            bf16x4_t hv = { (bf16_t)fmaxf(acc[0] + bv.x, 0.f),
                            (bf16_t)fmaxf(acc[1] + bv.y, 0.f),
                            (bf16_t)fmaxf(acc[2] + bv.z, 0.f),
                            (bf16_t)fmaxf(acc[3] + bv.w, 0.f) };
            *(bf16x4_t*)swzp<7>(h4, m * 16 + c, fg * 32 + q * 8) = hv;
        }
    };

    // ---- expert loop: X = {L2(e), L4(e-1)}, Y = {L3(e), L1(e+1), L5(e-1)} ----
    // Prefetch map:
    //   X(e): wCa(e)->L3.half1@Y(e) [cross-barrier], wA(e+1)->L1@Y(e) [cross-barrier]
    //   Y(e): wCb(e)->L3.half2 (covered by half1), wE(e-1)->L5 (covered by L1),
    //         wB(e+1)->L2@X(e+1), wD(e)->L4@X(e+1) [cross-barrier]
    for (int e = 0; e < NE; e++) {
        const bf16_t* We  = Wf + (size_t)e * 81920;
        const bf16_t* Wen = Wf + (size_t)((e + 1) & 31) * 81920;
        const bf16_t* Wep = Wf + (size_t)((e - 1) & 31) * 81920;

        // ---- X phase: issue wCa(e), wA(e+1) ----
#pragma unroll
        for (int ks = 0; ks < 8; ks++)
            wCa[ks] = *(const bf16x8*)(We + ((size_t)(64 + fg * 16 + ks) * 64 + lane) * 8);
#pragma unroll
        for (int ks = 0; ks < 8; ks++)
            wA[ks] = *(const bf16x8*)(Wen + ((size_t)(fg * 8 + ks) * 64 + lane) * 8);

        // L2(e) 32x32: h1 -> h2 (f-tiles fg*2..+1, rows mh half) — wB from Y(e-1)
        {
            bf16x8 ha[4];
#pragma unroll
            for (int ks = 0; ks < 4; ks++)
                ha[ks] = *(const bf16x8*)swzp<7>(h1, bb, ks * 32 + h * 16);
            f32x16 acc[2];
#pragma unroll
            for (int jt = 0; jt < 2; jt++)
#pragma unroll
                for (int r = 0; r < 16; r++) acc[jt][r] = 0.f;
#pragma unroll
            for (int jt = 0; jt < 2; jt++)
#pragma unroll
                for (int ks = 0; ks < 4; ks++)
                    acc[jt] = __builtin_amdgcn_mfma_f32_32x32x16_bf16(wB[jt][ks], ha[ks], acc[jt], 0, 0, 0);
#pragma unroll
            for (int jt = 0; jt < 2; jt++) {
                const int ft = fg * 2 + jt;
#pragma unroll
                for (int t = 0; t < 4; t++) {
                    const float4 bv = *(const float4*)(b2 + (size_t)e * H2D + ft * 32 + t * 8 + h * 4);
                    bf16x4_t hv = { (bf16_t)fmaxf(acc[jt][4 * t + 0] + bv.x, 0.f),
                                    (bf16_t)fmaxf(acc[jt][4 * t + 1] + bv.y, 0.f),
                                    (bf16_t)fmaxf(acc[jt][4 * t + 2] + bv.z, 0.f),
                                    (bf16_t)fmaxf(acc[jt][4 * t + 3] + bv.w, 0.f) };
                    *(bf16x4_t*)swzp<9>(h2, bb, ft * 64 + t * 16 + h * 8) = hv;
                }
            }
        }
        // L4(e-1): h3 -> h4 — wD from Y(e-1)
        if (e > 0) do_l4(e - 1);
        __syncthreads();

        // ---- Y phase ----
        // issue wCb(e) [L3 ks 8..15] — consumed after half-1
#pragma unroll
        for (int ks = 0; ks < 8; ks++)
            wCb[ks] = *(const bf16x8*)(We + ((size_t)(64 + fg * 16 + 8 + ks) * 64 + lane) * 8);

        // L3(e) 32x32: h2 -> h3 (f-tile fg, rows mh half), K software-pipelined
        {
            f32x16 acc;
#pragma unroll
            for (int r = 0; r < 16; r++) acc[r] = 0.f;
#pragma unroll
            for (int ks = 0; ks < 8; ks++) {
                bf16x8 ha = *(const bf16x8*)swzp<9>(h2, bb, ks * 32 + h * 16);
                acc = __builtin_amdgcn_mfma_f32_32x32x16_bf16(wCa[ks], ha, acc, 0, 0, 0);
            }
#pragma unroll
            for (int ks = 0; ks < 8; ks++) {
                bf16x8 ha = *(const bf16x8*)swzp<9>(h2, bb, (8 + ks) * 32 + h * 16);
                acc = __builtin_amdgcn_mfma_f32_32x32x16_bf16(wCb[ks], ha, acc, 0, 0, 0);
            }
#pragma unroll
            for (int t = 0; t < 4; t++) {
                const float4 bv = *(const float4*)(b3 + (size_t)e * H3D + fg * 32 + t * 8 + h * 4);
                bf16x4_t hv = { (bf16_t)fmaxf(acc[4 * t + 0] + bv.x, 0.f),
                                (bf16_t)fmaxf(acc[4 * t + 1] + bv.y, 0.f),
                                (bf16_t)fmaxf(acc[4 * t + 2] + bv.z, 0.f),
                                (bf16_t)fmaxf(acc[4 * t + 3] + bv.w, 0.f) };
                *(bf16x4_t*)swzp<8>(h3, bb, fg * 64 + t * 16 + h * 8) = hv;
            }
        }

        // issue wE(e-1), wB(e+1), wD(e) — covered by L1+L5 compute below
        if (e > 0) {
#pragma unroll
            for (int ks = 0; ks < 4; ks++)
                wE[ks] = *(const bf16x8*)(Wep + ((size_t)(144 + fg * 4 + ks) * 64 + lane) * 8);
        }
#pragma unroll
        for (int jt = 0; jt < 2; jt++)
#pragma unroll
            for (int ks = 0; ks < 4; ks++)
                wB[jt][ks] = *(const bf16x8*)(Wen + ((size_t)(32 + (fg * 2 + jt) * 4 + ks) * 64 + lane) * 8);
#pragma unroll
        for (int ks = 0; ks < 4; ks++)
            wD[ks] = *(const bf16x8*)(We + ((size_t)(128 + fg * 4 + ks) * 64 + lane) * 8);

        // L1(e+1) 16x16: sX -> h1 — wA from X(e)
        if (e < NE - 1) {
            const float4 bv = *(const float4*)(b1 + (size_t)(e + 1) * H1D + fg * 16 + q * 4);
#pragma unroll
            for (int mm = 0; mm < 2; mm++) {
                const int m = mh * 2 + mm;
                f32x4 acc = (f32x4){0.f, 0.f, 0.f, 0.f};
#pragma unroll
                for (int ks = 0; ks < 8; ks++) {
                    bf16x8 xv = *(const bf16x8*)swzp<9>(sX, m * 16 + c, ks * 64 + q * 16);
                    acc = __builtin_amdgcn_mfma_f32_16x16x32_bf16(wA[ks], xv, acc, 0, 0, 0);
                }
                bf16x4_t hv = { (bf16_t)fmaxf(acc[0] + bv.x, 0.f),
                                (bf16_t)fmaxf(acc[1] + bv.y, 0.f),
                                (bf16_t)fmaxf(acc[2] + bv.z, 0.f),
                                (bf16_t)fmaxf(acc[3] + bv.w, 0.f) };
                *(bf16x4_t*)swzp<7>(h1, m * 16 + c, fg * 32 + q * 8) = hv;
            }
        }
        // L5(e-1) 32x32: h4 -> oacc — wE covered by L1 above
        if (e > 0) do_l5(e - 1);
        __syncthreads();
    }

    // ---- epilogue: issue wE(31); L4(31) (wD from Y(31)); bar; L5(31) ----
#pragma unroll
    for (int ks = 0; ks < 4; ks++)
        wE[ks] = *(const bf16x8*)(Wf + (size_t)31 * 81920 + ((size_t)(144 + fg * 4 + ks) * 64 + lane) * 8);
    do_l4(NE - 1);
    __syncthreads();
    do_l5(NE - 1);

    // ---- store: lane owns row b0+bb, cols fg*32 + t*8 + h*4 .. +3 ----
#pragma unroll
    for (int t = 0; t < 4; t++)
        *(float4*)(out + (size_t)(b0 + bb) * NOUT + fg * 32 + t * 8 + h * 4) =
            (float4){oacc[4 * t + 0], oacc[4 * t + 1], oacc[4 * t + 2], oacc[4 * t + 3]};
}

extern "C" void kernel_launch(void* const* d_in, const int* in_sizes, int n_in,
                              void* d_out, int out_size, void* d_ws, size_t ws_size,
                              hipStream_t stream)
{
    (void)in_sizes; (void)n_in; (void)out_size; (void)ws_size;
    const float* x  = (const float*)d_in[0];
    const float* Wg = (const float*)d_in[1];
    const float* bg = (const float*)d_in[2];
    const float* W1 = (const float*)d_in[3];
    const float* b1 = (const float*)d_in[4];
    const float* W2 = (const float*)d_in[5];
    const float* b2 = (const float*)d_in[6];
    const float* W3 = (const float*)d_in[7];
    const float* b3 = (const float*)d_in[8];
    const float* W4 = (const float*)d_in[9];
    const float* b4 = (const float*)d_in[10];
    const float* W5 = (const float*)d_in[11];
    const float* b5 = (const float*)d_in[12];

    char* ws = (char*)d_ws;
    bf16_t* Wf  = (bf16_t*)(ws + OFF_WF);
    bf16_t* Wgf = (bf16_t*)(ws + OFF_WGF);
    float*  outp = (float*)d_out;

    build_frags<<<dim3(1284), dim3(256), 0, stream>>>(W1, W2, W3, W4, W5, Wg, Wf, Wgf);
    moe_main<<<dim3(BB / 64), dim3(512), 0, stream>>>(x, Wf, Wgf, bg,
                                                      b1, b2, b3, b4, b5, outp);
}

// Round 9
// 250.807 us; speedup vs baseline: 1.0803x; 1.0803x over previous
//
#include <hip/hip_runtime.h>

// Problem constants
#define BB      16384
#define IN_DIM  256
#define NE      32
#define H1D     64
#define H2D     256
#define H3D     128
#define NOUT    128

typedef __bf16 bf16_t;
typedef __bf16 bf16x4_t __attribute__((ext_vector_type(4)));
typedef __bf16 bf16x8  __attribute__((ext_vector_type(8)));
typedef float  f32x4   __attribute__((ext_vector_type(4)));
typedef float  f32x16  __attribute__((ext_vector_type(16)));

// ---- workspace: fragment-ordered bf16 weights ----
// Per expert, 160 "sets" of 64 lanes x 16B, contiguous in set order:
//   sets [0,32):    L1  16x16 (tile 0..3,  ks 0..7)   K=256, N=64
//   sets [32,64):   L2  32x32 (tile 0..7,  ks 0..3)   K=64,  N=256
//   sets [64,128):  L3  32x32 (tile 0..3,  ks 0..15)  K=256, N=128
//   sets [128,144): L4  16x16 (tile 0..3,  ks 0..3)   K=128, N=64
//   sets [144,160): L5  32x32 (tile 0..3,  ks 0..3)   K=64,  N=128
// 16x16 frag: dst[..+j] = W[ks*32+(l>>4)*8+j][t*16+(l&15)]
// 32x32 frag: dst[..+j] = W[ks*16+(l>>5)*8+j][t*32+(l&31)]
#define OFF_WF   ((size_t)0)
#define OFF_WGF  ((size_t)NE * 81920 * 2)     // Wg frags: 16 sets (16x16) = 16 KB

// ---- prep: one thread per fragment ----
__global__ __launch_bounds__(256) void build_frags(
    const float* __restrict__ W1, const float* __restrict__ W2,
    const float* __restrict__ W3, const float* __restrict__ W4,
    const float* __restrict__ W5, const float* __restrict__ Wg,
    bf16_t* __restrict__ Wf, bf16_t* __restrict__ Wgf)
{
    const int g    = blockIdx.x * 256 + threadIdx.x;
    const int lane = g & 63;
    const int set  = g >> 6;            // 0 .. 5135
    const float* src; bf16_t* dst; int N, t, ks; bool big;
    if (set < 5120) {
        const int e = set / 160;
        const int s = set % 160;
        dst = Wf + (size_t)e * 81920 + ((size_t)s * 64 + lane) * 8;
        if (s < 32)       { t = s >> 3;            ks = s & 7;          N = 64;  big = false; src = W1 + (size_t)e * 16384; }
        else if (s < 64)  { int r = s - 32;  t = r >> 2;  ks = r & 3;   N = 256; big = true;  src = W2 + (size_t)e * 16384; }
        else if (s < 128) { int r = s - 64;  t = r >> 4;  ks = r & 15;  N = 128; big = true;  src = W3 + (size_t)e * 32768; }
        else if (s < 144) { int r = s - 128; t = r >> 2;  ks = r & 3;   N = 64;  big = false; src = W4 + (size_t)e * 8192;  }
        else              { int r = s - 144; t = r >> 2;  ks = r & 3;   N = 128; big = true;  src = W5 + (size_t)e * 8192;  }
    } else {
        const int s = set - 5120;
        t = s >> 3; ks = s & 7; N = 32; big = false; src = Wg;
        dst = Wgf + ((size_t)s * 64 + lane) * 8;
    }
    int f, k0;
    if (big) { f = t * 32 + (lane & 31); k0 = ks * 16 + (lane >> 5) * 8; }
    else     { f = t * 16 + (lane & 15); k0 = ks * 32 + (lane >> 4) * 8; }
    bf16x8 o;
#pragma unroll
    for (int j = 0; j < 8; j++) o[j] = (bf16_t)src[(size_t)(k0 + j) * N + f];
    *(bf16x8*)dst = o;
}

// ---- swizzled LDS addressing: 16B-granule XOR with row&7 (bank-balanced) ----
template<int RS>
__device__ __forceinline__ void* swzp(char* base, int row, int byteoff) {
    const int g = byteoff >> 4;
    return (void*)(base + ((row << RS) | ((g ^ (row & 7)) << 4) | (byteoff & 15)));
}

// ---- LDS carve: 64-row tile ----
#define L_H1   0          // h1 [64][128B]  RS=7   8 KB
#define L_SX   8192       // x  [64][512B]  RS=9  32 KB
#define L_H2   40960      // h2 [64][512B]  RS=9  32 KB
#define L_H3   73728      // h3 [64][256B]  RS=8  16 KB (alias gating logits [64][36] f32)
#define L_H4   90112      // h4 [64][128B]  RS=7   8 KB
#define L_SG   98304      // g  [32e][64b] f32     8 KB
#define L_TOT  106496

// ---- main: 64-row tile, 8 waves, 256 blocks; 2 barriers/expert,
//      strict one-phase-ahead prefetch; L2/L3/L5 on 32x32x16.
//      __launch_bounds__(512, 1): LDS already limits to 1 block/CU, so let the
//      allocator use the full 256-VGPR budget (r3/r7 spills were the 128 cap). ----
__global__ __launch_bounds__(512, 1) void moe_main(
    const float* __restrict__ x, const bf16_t* __restrict__ Wf,
    const bf16_t* __restrict__ Wgf, const float* __restrict__ bg,
    const float* __restrict__ b1, const float* __restrict__ b2,
    const float* __restrict__ b3, const float* __restrict__ b4,
    const float* __restrict__ b5, float* __restrict__ out)
{
    __shared__ __align__(16) char lds[L_TOT];
    char* sX = lds + L_SX;
    char* h1 = lds + L_H1;
    char* h2 = lds + L_H2;
    char* h3 = lds + L_H3;
    char* h4 = lds + L_H4;
    float* sG = (float*)(lds + L_SG);

    const int tid  = threadIdx.x;
    const int w    = tid >> 6;
    const int lane = tid & 63;
    const int c    = lane & 15;          // 16x16 lane mapping
    const int q    = lane >> 4;
    const int c2   = lane & 31;          // 32x32 lane mapping
    const int h    = lane >> 5;
    const int fg   = w & 3;              // f-tile index (all layers)
    const int mh   = w >> 2;             // m-half
    const int bb   = mh * 32 + c2;       // batch row for 32x32 layers
    const int b0   = blockIdx.x * 64;

    bf16x8 wA[8], wB[2][4], wC[16], wD[4], wE[4];

    // early issue: wA(0) [L1 tile fg], wB(0) [L2 tiles fg*2..+1]
#pragma unroll
    for (int ks = 0; ks < 8; ks++)
        wA[ks] = *(const bf16x8*)(Wf + ((size_t)(fg * 8 + ks) * 64 + lane) * 8);
#pragma unroll
    for (int jt = 0; jt < 2; jt++)
#pragma unroll
        for (int ks = 0; ks < 4; ks++)
            wB[jt][ks] = *(const bf16x8*)(Wf + ((size_t)(32 + (fg * 2 + jt) * 4 + ks) * 64 + lane) * 8);

    // ---- stage x: 64x256 fp32 -> bf16, swizzled ----
    {
        const int r  = tid >> 3;
        const int c0 = (tid & 7) * 32;
        const float* sp = x + (size_t)(b0 + r) * IN_DIM + c0;
#pragma unroll
        for (int jj = 0; jj < 4; jj++) {
            const float4 v0 = *(const float4*)(sp + jj * 8);
            const float4 v1 = *(const float4*)(sp + jj * 8 + 4);
            bf16x8 o = { (bf16_t)v0.x, (bf16_t)v0.y, (bf16_t)v0.z, (bf16_t)v0.w,
                         (bf16_t)v1.x, (bf16_t)v1.y, (bf16_t)v1.z, (bf16_t)v1.w };
            *(bf16x8*)swzp<9>(sX, r, c0 * 2 + jj * 16) = o;
        }
    }
    __syncthreads();

    // ---- gating logits -> h3 alias [64][36] f32 (16x16) ----
    {
        const int t = w & 1, m = w >> 1;
        f32x4 acc = (f32x4){0.f, 0.f, 0.f, 0.f};
#pragma unroll
        for (int ks = 0; ks < 8; ks++) {
            bf16x8 xv = *(const bf16x8*)swzp<9>(sX, m * 16 + c, ks * 64 + q * 16);
            bf16x8 wg = *(const bf16x8*)(Wgf + ((size_t)(t * 8 + ks) * 64 + lane) * 8);
            acc = __builtin_amdgcn_mfma_f32_16x16x32_bf16(wg, xv, acc, 0, 0, 0);
        }
        const float4 bgv = *(const float4*)(bg + t * 16 + q * 4);
        float* sLgF = (float*)h3;
        *(float4*)(sLgF + (size_t)(m * 16 + c) * 36 + t * 16 + q * 4) =
            (float4){acc[0] + bgv.x, acc[1] + bgv.y, acc[2] + bgv.z, acc[3] + bgv.w};
    }
    __syncthreads();

    // ---- softmax -> sG ; L1(0): sX -> h1 ----
    {
        const int r = tid >> 3;
        const int j = tid & 7;
        const float* sLgF = (const float*)h3;
        float4 l = *(const float4*)(sLgF + (size_t)r * 36 + j * 4);
        float mx = fmaxf(fmaxf(l.x, l.y), fmaxf(l.z, l.w));
#pragma unroll
        for (int off = 1; off < 8; off <<= 1) mx = fmaxf(mx, __shfl_xor(mx, off));
        float e0 = __expf(l.x - mx), e1 = __expf(l.y - mx),
              e2 = __expf(l.z - mx), e3 = __expf(l.w - mx);
        float sm = e0 + e1 + e2 + e3;
#pragma unroll
        for (int off = 1; off < 8; off <<= 1) sm += __shfl_xor(sm, off);
        const float rs = 1.f / sm;
        sG[(j * 4 + 0) * 64 + r] = e0 * rs;
        sG[(j * 4 + 1) * 64 + r] = e1 * rs;
        sG[(j * 4 + 2) * 64 + r] = e2 * rs;
        sG[(j * 4 + 3) * 64 + r] = e3 * rs;
    }
    {
        const float4 bv = *(const float4*)(b1 + fg * 16 + q * 4);
#pragma unroll
        for (int mm = 0; mm < 2; mm++) {
            const int m = mh * 2 + mm;
            f32x4 acc = (f32x4){0.f, 0.f, 0.f, 0.f};
#pragma unroll
            for (int ks = 0; ks < 8; ks++) {
                bf16x8 xv = *(const bf16x8*)swzp<9>(sX, m * 16 + c, ks * 64 + q * 16);
                acc = __builtin_amdgcn_mfma_f32_16x16x32_bf16(wA[ks], xv, acc, 0, 0, 0);
            }
            bf16x4_t hv = { (bf16_t)fmaxf(acc[0] + bv.x, 0.f),
                            (bf16_t)fmaxf(acc[1] + bv.y, 0.f),
                            (bf16_t)fmaxf(acc[2] + bv.z, 0.f),
                            (bf16_t)fmaxf(acc[3] + bv.w, 0.f) };
            *(bf16x4_t*)swzp<7>(h1, m * 16 + c, fg * 32 + q * 8) = hv;
        }
    }
    __syncthreads();

    float oacc[16];
#pragma unroll
    for (int r = 0; r < 16; r++) oacc[r] = 0.f;

    auto do_l5 = [&](int ep) {   // 32x32: h4 -> oacc, f-tile fg, m-half mh (wE prefetched)
        f32x16 p;
#pragma unroll
        for (int r = 0; r < 16; r++) p[r] = 0.f;
#pragma unroll
        for (int ks = 0; ks < 4; ks++) {
            bf16x8 ha = *(const bf16x8*)swzp<7>(h4, bb, ks * 32 + h * 16);
            p = __builtin_amdgcn_mfma_f32_32x32x16_bf16(wE[ks], ha, p, 0, 0, 0);
        }
        const float gv = sG[ep * 64 + bb];
#pragma unroll
        for (int t = 0; t < 4; t++) {
            const float4 bv = *(const float4*)(b5 + (size_t)ep * NOUT + fg * 32 + t * 8 + h * 4);
            oacc[4 * t + 0] += gv * (p[4 * t + 0] + bv.x);
            oacc[4 * t + 1] += gv * (p[4 * t + 1] + bv.y);
            oacc[4 * t + 2] += gv * (p[4 * t + 2] + bv.z);
            oacc[4 * t + 3] += gv * (p[4 * t + 3] + bv.w);
        }
    };

    auto do_l4 = [&](int ep) {   // 16x16: h3 -> h4, f-tile fg, rows mh half (wD prefetched)
        const float4 bv = *(const float4*)(b4 + (size_t)ep * H1D + fg * 16 + q * 4);
#pragma unroll
        for (int mm = 0; mm < 2; mm++) {
            const int m = mh * 2 + mm;
            f32x4 acc = (f32x4){0.f, 0.f, 0.f, 0.f};
#pragma unroll
            for (int ks = 0; ks < 4; ks++) {
                bf16x8 ha = *(const bf16x8*)swzp<8>(h3, m * 16 + c, ks * 64 + q * 16);
                acc = __builtin_amdgcn_mfma_f32_16x16x32_bf16(wD[ks], ha, acc, 0, 0, 0);
            }
            bf16x4_t hv = { (bf16_t)fmaxf(acc[0] + bv.x, 0.f),
                            (bf16_t)fmaxf(acc[1] + bv.y, 0.f),
                            (bf16_t)fmaxf(acc[2] + bv.z, 0.f),
                            (bf16_t)fmaxf(acc[3] + bv.w, 0.f) };
            *(bf16x4_t*)swzp<7>(h4, m * 16 + c, fg * 32 + q * 8) = hv;
        }
    };

    // ---- expert loop: X = {L2(e), L4(e-1)}, Y = {L3(e), L1(e+1), L5(e-1)} ----
    // Prefetch map (one phase ahead or covered):
    //   X(e): wC(e)->L3@Y(e), wA(e+1)->L1@Y(e)
    //   Y(e): wE(e-1)->L5@Y(e) (covered by L3+L1), wB(e+1)->L2@X(e+1), wD(e)->L4@X(e+1)
    for (int e = 0; e < NE; e++) {
        const bf16_t* We  = Wf + (size_t)e * 81920;
        const bf16_t* Wen = Wf + (size_t)((e + 1) & 31) * 81920;
        const bf16_t* Wep = Wf + (size_t)((e - 1) & 31) * 81920;

        // ---- X phase: issue wC(e), wA(e+1) ----
#pragma unroll
        for (int ks = 0; ks < 16; ks++)
            wC[ks] = *(const bf16x8*)(We + ((size_t)(64 + fg * 16 + ks) * 64 + lane) * 8);
#pragma unroll
        for (int ks = 0; ks < 8; ks++)
            wA[ks] = *(const bf16x8*)(Wen + ((size_t)(fg * 8 + ks) * 64 + lane) * 8);

        // L2(e) 32x32: h1 -> h2 (f-tiles fg*2..+1, rows mh half) — wB from Y(e-1)
        {
            bf16x8 ha[4];
#pragma unroll
            for (int ks = 0; ks < 4; ks++)
                ha[ks] = *(const bf16x8*)swzp<7>(h1, bb, ks * 32 + h * 16);
            f32x16 acc[2];
#pragma unroll
            for (int jt = 0; jt < 2; jt++)
#pragma unroll
                for (int r = 0; r < 16; r++) acc[jt][r] = 0.f;
#pragma unroll
            for (int jt = 0; jt < 2; jt++)
#pragma unroll
                for (int ks = 0; ks < 4; ks++)
                    acc[jt] = __builtin_amdgcn_mfma_f32_32x32x16_bf16(wB[jt][ks], ha[ks], acc[jt], 0, 0, 0);
#pragma unroll
            for (int jt = 0; jt < 2; jt++) {
                const int ft = fg * 2 + jt;
#pragma unroll
                for (int t = 0; t < 4; t++) {
                    const float4 bv = *(const float4*)(b2 + (size_t)e * H2D + ft * 32 + t * 8 + h * 4);
                    bf16x4_t hv = { (bf16_t)fmaxf(acc[jt][4 * t + 0] + bv.x, 0.f),
                                    (bf16_t)fmaxf(acc[jt][4 * t + 1] + bv.y, 0.f),
                                    (bf16_t)fmaxf(acc[jt][4 * t + 2] + bv.z, 0.f),
                                    (bf16_t)fmaxf(acc[jt][4 * t + 3] + bv.w, 0.f) };
                    *(bf16x4_t*)swzp<9>(h2, bb, ft * 64 + t * 16 + h * 8) = hv;
                }
            }
        }
        // L4(e-1): h3 -> h4 — wD from Y(e-1)
        if (e > 0) do_l4(e - 1);
        __syncthreads();

        // ---- Y phase: issue wE(e-1), wB(e+1), wD(e) ----
        if (e > 0) {
#pragma unroll
            for (int ks = 0; ks < 4; ks++)
                wE[ks] = *(const bf16x8*)(Wep + ((size_t)(144 + fg * 4 + ks) * 64 + lane) * 8);
        }
#pragma unroll
        for (int jt = 0; jt < 2; jt++)
#pragma unroll
            for (int ks = 0; ks < 4; ks++)
                wB[jt][ks] = *(const bf16x8*)(Wen + ((size_t)(32 + (fg * 2 + jt) * 4 + ks) * 64 + lane) * 8);
#pragma unroll
        for (int ks = 0; ks < 4; ks++)
            wD[ks] = *(const bf16x8*)(We + ((size_t)(128 + fg * 4 + ks) * 64 + lane) * 8);

        // L3(e) 32x32: h2 -> h3 (f-tile fg, rows mh half) — wC from X(e)
        {
            f32x16 acc;
#pragma unroll
            for (int r = 0; r < 16; r++) acc[r] = 0.f;
#pragma unroll
            for (int ks = 0; ks < 16; ks++) {
                bf16x8 ha = *(const bf16x8*)swzp<9>(h2, bb, ks * 32 + h * 16);
                acc = __builtin_amdgcn_mfma_f32_32x32x16_bf16(wC[ks], ha, acc, 0, 0, 0);
            }
#pragma unroll
            for (int t = 0; t < 4; t++) {
                const float4 bv = *(const float4*)(b3 + (size_t)e * H3D + fg * 32 + t * 8 + h * 4);
                bf16x4_t hv = { (bf16_t)fmaxf(acc[4 * t + 0] + bv.x, 0.f),
                                (bf16_t)fmaxf(acc[4 * t + 1] + bv.y, 0.f),
                                (bf16_t)fmaxf(acc[4 * t + 2] + bv.z, 0.f),
                                (bf16_t)fmaxf(acc[4 * t + 3] + bv.w, 0.f) };
                *(bf16x4_t*)swzp<8>(h3, bb, fg * 64 + t * 16 + h * 8) = hv;
            }
        }
        // L1(e+1) 16x16: sX -> h1 — wA from X(e)
        if (e < NE - 1) {
            const float4 bv = *(const float4*)(b1 + (size_t)(e + 1) * H1D + fg * 16 + q * 4);
#pragma unroll
            for (int mm = 0; mm < 2; mm++) {
                const int m = mh * 2 + mm;
                f32x4 acc = (f32x4){0.f, 0.f, 0.f, 0.f};
#pragma unroll
                for (int ks = 0; ks < 8; ks++) {
                    bf16x8 xv = *(const bf16x8*)swzp<9>(sX, m * 16 + c, ks * 64 + q * 16);
                    acc = __builtin_amdgcn_mfma_f32_16x16x32_bf16(wA[ks], xv, acc, 0, 0, 0);
                }
                bf16x4_t hv = { (bf16_t)fmaxf(acc[0] + bv.x, 0.f),
                                (bf16_t)fmaxf(acc[1] + bv.y, 0.f),
                                (bf16_t)fmaxf(acc[2] + bv.z, 0.f),
                                (bf16_t)fmaxf(acc[3] + bv.w, 0.f) };
                *(bf16x4_t*)swzp<7>(h1, m * 16 + c, fg * 32 + q * 8) = hv;
            }
        }
        // L5(e-1) 32x32: h4 -> oacc — wE covered by L3+L1 above
        if (e > 0) do_l5(e - 1);
        __syncthreads();
    }

    // ---- epilogue: issue wE(31); L4(31) (wD from Y(31)); bar; L5(31) ----
#pragma unroll
    for (int ks = 0; ks < 4; ks++)
        wE[ks] = *(const bf16x8*)(Wf + (size_t)31 * 81920 + ((size_t)(144 + fg * 4 + ks) * 64 + lane) * 8);
    do_l4(NE - 1);
    __syncthreads();
    do_l5(NE - 1);

    // ---- store: lane owns row b0+bb, cols fg*32 + t*8 + h*4 .. +3 ----
#pragma unroll
    for (int t = 0; t < 4; t++)
        *(float4*)(out + (size_t)(b0 + bb) * NOUT + fg * 32 + t * 8 + h * 4) =
            (float4){oacc[4 * t + 0], oacc[4 * t + 1], oacc[4 * t + 2], oacc[4 * t + 3]};
}

extern "C" void kernel_launch(void* const* d_in, const int* in_sizes, int n_in,
                              void* d_out, int out_size, void* d_ws, size_t ws_size,
                              hipStream_t stream)
{
    (void)in_sizes; (void)n_in; (void)out_size; (void)ws_size;
    const float* x  = (const float*)d_in[0];
    const float* Wg = (const float*)d_in[1];
    const float* bg = (const float*)d_in[2];
    const float* W1 = (const float*)d_in[3];
    const float* b1 = (const float*)d_in[4];
    const float* W2 = (const float*)d_in[5];
    const float* b2 = (const float*)d_in[6];
    const float* W3 = (const float*)d_in[7];
    const float* b3 = (const float*)d_in[8];
    const float* W4 = (const float*)d_in[9];
    const float* b4 = (const float*)d_in[10];
    const float* W5 = (const float*)d_in[11];
    const float* b5 = (const float*)d_in[12];

    char* ws = (char*)d_ws;
    bf16_t* Wf  = (bf16_t*)(ws + OFF_WF);
    bf16_t* Wgf = (bf16_t*)(ws + OFF_WGF);
    float*  outp = (float*)d_out;

    build_frags<<<dim3(1284), dim3(256), 0, stream>>>(W1, W2, W3, W4, W5, Wg, Wf, Wgf);
    moe_main<<<dim3(BB / 64), dim3(512), 0, stream>>>(x, Wf, Wgf, bg,
                                                      b1, b2, b3, b4, b5, outp);
}

// Round 11
// 224.362 us; speedup vs baseline: 1.2077x; 1.1179x over previous
//
#include <hip/hip_runtime.h>

// Problem constants
#define BB      16384
#define IN_DIM  256
#define NE      32
#define H1D     64
#define H2D     256
#define H3D     128
#define NOUT    128

typedef __bf16 bf16_t;
typedef __bf16 bf16x4_t __attribute__((ext_vector_type(4)));
typedef __bf16 bf16x8  __attribute__((ext_vector_type(8)));
typedef float  f32x4   __attribute__((ext_vector_type(4)));

// ---- workspace: fragment-ordered bf16 weights (r6 layout, all 16x16) ----
// Per expert, 160 "sets" of 64 lanes x 16B, contiguous in set order:
//   sets [0,32):   L1  (tile 0..3, ks 0..7)   K=256, N=64
//   sets [32,64):  L2  (tile 0..15, ks 0..1)  K=64,  N=256
//   sets [64,128): L3  (tile 0..7,  ks 0..7)  K=256, N=128
//   sets [128,144):L4  (tile 0..3,  ks 0..3)  K=128, N=64
//   sets [144,160):L5  (tile 0..7,  ks 0..1)  K=64,  N=128
// frag elem: dst[(set*64+lane)*8 + j] = W[k0+j][t*16+(lane&15)], k0=ks*32+(lane>>4)*8
#define OFF_WF   ((size_t)0)
#define OFF_WGF  ((size_t)NE * 81920 * 2)     // Wg frags: 16 sets = 16 KB

// ---- prep v2 (fixed): LDS-tiled, fully coalesced transpose-to-frags ----
// One block per 64x64 (or 64x32 for Wg) source tile: float4 loads -> LDS ->
// per-set gather -> one bf16x8 (16B) coalesced store per thread-pass.
// r10 BUG: staging guard `if (N >= 64 || nsets == 8)` skipped staging for the
// Wg jobs (N=32, nsets=4) -> gather read uninitialized LDS -> absmax 0.119.
// Fix: staging ALWAYS runs; nsets only selects the staging shape.
__global__ __launch_bounds__(256) void build_frags(
    const float* __restrict__ W1, const float* __restrict__ W2,
    const float* __restrict__ W3, const float* __restrict__ W4,
    const float* __restrict__ W5, const float* __restrict__ Wg,
    bf16_t* __restrict__ Wf, bf16_t* __restrict__ Wgf)
{
    __shared__ float tile[64][65];
    const int b   = blockIdx.x;
    const int tid = threadIdx.x;

    const float* src;       // source matrix [K][N], fp32
    bf16_t* dstE;           // per-expert (or Wg) frag base
    int N, k0, f0, sbase, sstep, nsets;

    if (b < 640) {
        const int e = b / 20, j = b % 20;
        dstE = Wf + (size_t)e * 81920;
        if (j < 4)       { src = W1 + (size_t)e * 16384; N = 64;  k0 = j * 64;        f0 = 0;
                           sbase = j * 2;                sstep = 8; nsets = 8; }       // s = lt*8 + kt*2+lk
        else if (j < 8)  { src = W2 + (size_t)e * 16384; N = 256; k0 = 0;             f0 = (j - 4) * 64;
                           sbase = 32 + (j - 4) * 8;     sstep = 2; nsets = 8; }       // s = 32 + (ft*4+lt)*2+lk
        else if (j < 16) { const int r = j - 8; const int kt = r & 3, ft = r >> 2;
                           src = W3 + (size_t)e * 32768; N = 128; k0 = kt * 64;       f0 = ft * 64;
                           sbase = 64 + ft * 32 + kt * 2; sstep = 8; nsets = 8; }      // s = 64 + (ft*4+lt)*8 + kt*2+lk
        else if (j < 18) { src = W4 + (size_t)e * 8192;  N = 64;  k0 = (j - 16) * 64; f0 = 0;
                           sbase = 128 + (j - 16) * 2;   sstep = 4; nsets = 8; }       // s = 128 + lt*4 + kt*2+lk
        else             { src = W5 + (size_t)e * 8192;  N = 128; k0 = 0;             f0 = (j - 18) * 64;
                           sbase = 144 + (j - 18) * 8;   sstep = 2; nsets = 8; }       // s = 144 + (ft*4+lt)*2+lk
    } else {
        const int kt = b - 640;                  // Wg [256][32]: 4 k-tiles of 64x32
        src = Wg; dstE = Wgf; N = 32; k0 = kt * 64; f0 = 0;
        sbase = kt * 2; sstep = 8; nsets = 4;    // s = lt*8 + kt*2+lk, lt in 0..1
    }

    // ---- stage source tile into LDS (fully coalesced float4) — ALWAYS ----
    if (nsets == 8) {
        // 64 rows x 64 cols: thread -> 4 float4 (row tid>>4 + i*16, col (tid&15)*4)
        const int r = tid >> 4, cc = (tid & 15) * 4;
#pragma unroll
        for (int i = 0; i < 4; i++) {
            const float4 v = *(const float4*)(src + (size_t)(k0 + r + i * 16) * N + f0 + cc);
            tile[r + i * 16][cc + 0] = v.x; tile[r + i * 16][cc + 1] = v.y;
            tile[r + i * 16][cc + 2] = v.z; tile[r + i * 16][cc + 3] = v.w;
        }
    } else {
        // Wg: 64 rows x 32 cols: thread -> 2 float4 (row tid>>3 + i*32, col (tid&7)*4)
        const int r = tid >> 3, cc = (tid & 7) * 4;
#pragma unroll
        for (int i = 0; i < 2; i++) {
            const float4 v = *(const float4*)(src + (size_t)(k0 + r + i * 32) * N + cc);
            tile[r + i * 32][cc + 0] = v.x; tile[r + i * 32][cc + 1] = v.y;
            tile[r + i * 32][cc + 2] = v.z; tile[r + i * 32][cc + 3] = v.w;
        }
    }
    __syncthreads();

    // ---- gather + store: 4 sets per pass (set = tid>>6, lane = tid&63) ----
    const int lane = tid & 63;
    const int fl16 = lane & 15;
    const int kq   = (lane >> 4) * 8;
    const int passes = nsets >> 2;
    for (int p = 0; p < passes; p++) {
        const int ls = p * 4 + (tid >> 6);       // local set: lt*2 + lk
        const int lt = ls >> 1, lk = ls & 1;
        const int s  = sbase + lt * sstep + lk;
        const int kl = lk * 32 + kq;
        const int fl = lt * 16 + fl16;
        bf16x8 o;
#pragma unroll
        for (int jj = 0; jj < 8; jj++) o[jj] = (bf16_t)tile[kl + jj][fl];
        *(bf16x8*)(dstE + ((size_t)s * 64 + lane) * 8) = o;
    }
}

// ---- swizzled LDS addressing: 16B-granule XOR with row&7 (bank-balanced) ----
template<int RS>
__device__ __forceinline__ void* swzp(char* base, int row, int byteoff) {
    const int g = byteoff >> 4;
    return (void*)(base + ((row << RS) | ((g ^ (row & 7)) << 4) | (byteoff & 15)));
}

// ---- LDS carve: 64-row tile ----
#define L_H1   0          // h1 [64][128B]  RS=7   8 KB
#define L_SX   8192       // x  [64][512B]  RS=9  32 KB
#define L_H2   40960      // h2 [64][512B]  RS=9  32 KB
#define L_H3   73728      // h3 [64][256B]  RS=8  16 KB (alias gating logits [64][36] f32)
#define L_H4   90112      // h4 [64][128B]  RS=7   8 KB
#define L_SG   98304      // g  [32e][64b] f32     8 KB
#define L_TOT  106496

// ---- main: r6 verbatim — 64-row tile, 8 waves, 256 blocks; 2 barriers/expert,
//      strict one-phase-ahead weight prefetch, all 16x16 MFMA (no spill) ----
__global__ __launch_bounds__(512) void moe_main(
    const float* __restrict__ x, const bf16_t* __restrict__ Wf,
    const bf16_t* __restrict__ Wgf, const float* __restrict__ bg,
    const float* __restrict__ b1, const float* __restrict__ b2,
    const float* __restrict__ b3, const float* __restrict__ b4,
    const float* __restrict__ b5, float* __restrict__ out)
{
    __shared__ __align__(16) char lds[L_TOT];
    char* sX = lds + L_SX;
    char* h1 = lds + L_H1;
    char* h2 = lds + L_H2;
    char* h3 = lds + L_H3;
    char* h4 = lds + L_H4;
    float* sG = (float*)(lds + L_SG);

    const int tid  = threadIdx.x;
    const int w    = tid >> 6;
    const int lane = tid & 63;
    const int c    = lane & 15;
    const int q    = lane >> 4;
    const int fg   = w & 3;             // f-tile for L1/L4
    const int mh   = w >> 2;            // m-half for L1/L4
    const int b0   = blockIdx.x * 64;

    bf16x8 wA[8], wB[2][2], wC[8], wD[4], wE[2];

    // early issue: wA(0) [L1 tile fg], wB(0) [L2 tiles w*2..+1]
#pragma unroll
    for (int ks = 0; ks < 8; ks++)
        wA[ks] = *(const bf16x8*)(Wf + ((size_t)(fg * 8 + ks) * 64 + lane) * 8);
#pragma unroll
    for (int nt = 0; nt < 2; nt++)
#pragma unroll
        for (int ks = 0; ks < 2; ks++)
            wB[nt][ks] = *(const bf16x8*)(Wf + 16384 + ((size_t)((w * 2 + nt) * 2 + ks) * 64 + lane) * 8);

    // ---- stage x: 64x256 fp32 -> bf16, swizzled ----
    {
        const int r  = tid >> 3;
        const int c0 = (tid & 7) * 32;
        const float* sp = x + (size_t)(b0 + r) * IN_DIM + c0;
#pragma unroll
        for (int jj = 0; jj < 4; jj++) {
            const float4 v0 = *(const float4*)(sp + jj * 8);
            const float4 v1 = *(const float4*)(sp + jj * 8 + 4);
            bf16x8 o = { (bf16_t)v0.x, (bf16_t)v0.y, (bf16_t)v0.z, (bf16_t)v0.w,
                         (bf16_t)v1.x, (bf16_t)v1.y, (bf16_t)v1.z, (bf16_t)v1.w };
            *(bf16x8*)swzp<9>(sX, r, c0 * 2 + jj * 16) = o;
        }
    }
    __syncthreads();

    // ---- gating logits -> h3 alias [64][36] f32 ----
    {
        const int t = w & 1, m = w >> 1;
        f32x4 acc = (f32x4){0.f, 0.f, 0.f, 0.f};
#pragma unroll
        for (int ks = 0; ks < 8; ks++) {
            bf16x8 xv = *(const bf16x8*)swzp<9>(sX, m * 16 + c, ks * 64 + q * 16);
            bf16x8 wg = *(const bf16x8*)(Wgf + ((size_t)(t * 8 + ks) * 64 + lane) * 8);
            acc = __builtin_amdgcn_mfma_f32_16x16x32_bf16(wg, xv, acc, 0, 0, 0);
        }
        const float4 bgv = *(const float4*)(bg + t * 16 + q * 4);
        float* sLgF = (float*)h3;
        *(float4*)(sLgF + (size_t)(m * 16 + c) * 36 + t * 16 + q * 4) =
            (float4){acc[0] + bgv.x, acc[1] + bgv.y, acc[2] + bgv.z, acc[3] + bgv.w};
    }
    __syncthreads();

    // ---- softmax -> sG ; L1(0): sX -> h1 ----
    {
        const int r = tid >> 3;
        const int j = tid & 7;
        const float* sLgF = (const float*)h3;
        float4 l = *(const float4*)(sLgF + (size_t)r * 36 + j * 4);
        float mx = fmaxf(fmaxf(l.x, l.y), fmaxf(l.z, l.w));
#pragma unroll
        for (int off = 1; off < 8; off <<= 1) mx = fmaxf(mx, __shfl_xor(mx, off));
        float e0 = __expf(l.x - mx), e1 = __expf(l.y - mx),
              e2 = __expf(l.z - mx), e3 = __expf(l.w - mx);
        float sm = e0 + e1 + e2 + e3;
#pragma unroll
        for (int off = 1; off < 8; off <<= 1) sm += __shfl_xor(sm, off);
        const float rs = 1.f / sm;
        sG[(j * 4 + 0) * 64 + r] = e0 * rs;
        sG[(j * 4 + 1) * 64 + r] = e1 * rs;
        sG[(j * 4 + 2) * 64 + r] = e2 * rs;
        sG[(j * 4 + 3) * 64 + r] = e3 * rs;
    }
    {
        const float4 bv = *(const float4*)(b1 + fg * 16 + q * 4);
#pragma unroll
        for (int mm = 0; mm < 2; mm++) {
            const int m = mh * 2 + mm;
            f32x4 acc = (f32x4){0.f, 0.f, 0.f, 0.f};
#pragma unroll
            for (int ks = 0; ks < 8; ks++) {
                bf16x8 xv = *(const bf16x8*)swzp<9>(sX, m * 16 + c, ks * 64 + q * 16);
                acc = __builtin_amdgcn_mfma_f32_16x16x32_bf16(wA[ks], xv, acc, 0, 0, 0);
            }
            bf16x4_t hv = { (bf16_t)fmaxf(acc[0] + bv.x, 0.f),
                            (bf16_t)fmaxf(acc[1] + bv.y, 0.f),
                            (bf16_t)fmaxf(acc[2] + bv.z, 0.f),
                            (bf16_t)fmaxf(acc[3] + bv.w, 0.f) };
            *(bf16x4_t*)swzp<7>(h1, m * 16 + c, fg * 32 + q * 8) = hv;
        }
    }
    __syncthreads();

    float oacc[4][4];
#pragma unroll
    for (int m = 0; m < 4; m++)
#pragma unroll
        for (int r = 0; r < 4; r++) oacc[m][r] = 0.f;

    auto do_l5 = [&](int ep) {   // h4 -> oacc, f-tile w, all m (wE prefetched)
        const float4 bv = *(const float4*)(b5 + (size_t)ep * NOUT + w * 16 + q * 4);
#pragma unroll
        for (int m = 0; m < 4; m++) {
            f32x4 acc = (f32x4){0.f, 0.f, 0.f, 0.f};
#pragma unroll
            for (int ks = 0; ks < 2; ks++) {
                bf16x8 ha = *(const bf16x8*)swzp<7>(h4, m * 16 + c, ks * 64 + q * 16);
                acc = __builtin_amdgcn_mfma_f32_16x16x32_bf16(wE[ks], ha, acc, 0, 0, 0);
            }
            const float gv = sG[ep * 64 + m * 16 + c];
            oacc[m][0] += gv * (acc[0] + bv.x);
            oacc[m][1] += gv * (acc[1] + bv.y);
            oacc[m][2] += gv * (acc[2] + bv.z);
            oacc[m][3] += gv * (acc[3] + bv.w);
        }
    };

    auto do_l4 = [&](int ep) {   // h3 -> h4, f-tile fg, rows mh half (wD prefetched)
        const float4 bv = *(const float4*)(b4 + (size_t)ep * H1D + fg * 16 + q * 4);
#pragma unroll
        for (int mm = 0; mm < 2; mm++) {
            const int m = mh * 2 + mm;
            f32x4 acc = (f32x4){0.f, 0.f, 0.f, 0.f};
#pragma unroll
            for (int ks = 0; ks < 4; ks++) {
                bf16x8 ha = *(const bf16x8*)swzp<8>(h3, m * 16 + c, ks * 64 + q * 16);
                acc = __builtin_amdgcn_mfma_f32_16x16x32_bf16(wD[ks], ha, acc, 0, 0, 0);
            }
            bf16x4_t hv = { (bf16_t)fmaxf(acc[0] + bv.x, 0.f),
                            (bf16_t)fmaxf(acc[1] + bv.y, 0.f),
                            (bf16_t)fmaxf(acc[2] + bv.z, 0.f),
                            (bf16_t)fmaxf(acc[3] + bv.w, 0.f) };
            *(bf16x4_t*)swzp<7>(h4, m * 16 + c, fg * 32 + q * 8) = hv;
        }
    };

    // ---- expert loop: X = {L2(e), L4(e-1)}, Y = {L3(e), L1(e+1), L5(e-1)} ----
    // Prefetch map (issue -> use, always one phase ahead or covered):
    //   X(e) issues wC(e)   -> L3(e)   in Y(e)   [cross-barrier]
    //   X(e) issues wA(e+1) -> L1(e+1) in Y(e)   [cross-barrier]
    //   Y(e) issues wE(e-1) -> L5(e-1) in Y(e)   [covered by L3+L1 compute]
    //   Y(e) issues wB(e+1) -> L2(e+1) in X(e+1) [cross-barrier]
    //   Y(e) issues wD(e)   -> L4(e)   in X(e+1) [cross-barrier]
    for (int e = 0; e < NE; e++) {
        const bf16_t* We  = Wf + (size_t)e * 81920;
        const bf16_t* Wen = Wf + (size_t)((e + 1) & 31) * 81920;
        const bf16_t* Wep = Wf + (size_t)((e - 1) & 31) * 81920;

        // ---- X phase: issue wC(e), wA(e+1) ----
#pragma unroll
        for (int ks = 0; ks < 8; ks++)
            wC[ks] = *(const bf16x8*)(We + 32768 + ((size_t)(w * 8 + ks) * 64 + lane) * 8);
#pragma unroll
        for (int ks = 0; ks < 8; ks++)
            wA[ks] = *(const bf16x8*)(Wen + ((size_t)(fg * 8 + ks) * 64 + lane) * 8);

        // L2(e): h1 -> h2 (tiles w*2..+1, all m) — wB prefetched in Y(e-1)
        {
            float4 bv[2];
#pragma unroll
            for (int nt = 0; nt < 2; nt++)
                bv[nt] = *(const float4*)(b2 + (size_t)e * H2D + (w * 2 + nt) * 16 + q * 4);
#pragma unroll
            for (int m = 0; m < 4; m++) {
                bf16x8 ha[2];
#pragma unroll
                for (int ks = 0; ks < 2; ks++)
                    ha[ks] = *(const bf16x8*)swzp<7>(h1, m * 16 + c, ks * 64 + q * 16);
                f32x4 acc[2];
#pragma unroll
                for (int nt = 0; nt < 2; nt++) acc[nt] = (f32x4){0.f, 0.f, 0.f, 0.f};
#pragma unroll
                for (int nt = 0; nt < 2; nt++)
#pragma unroll
                    for (int ks = 0; ks < 2; ks++)
                        acc[nt] = __builtin_amdgcn_mfma_f32_16x16x32_bf16(wB[nt][ks], ha[ks], acc[nt], 0, 0, 0);
#pragma unroll
                for (int nt = 0; nt < 2; nt++) {
                    bf16x4_t hv = { (bf16_t)fmaxf(acc[nt][0] + bv[nt].x, 0.f),
                                    (bf16_t)fmaxf(acc[nt][1] + bv[nt].y, 0.f),
                                    (bf16_t)fmaxf(acc[nt][2] + bv[nt].z, 0.f),
                                    (bf16_t)fmaxf(acc[nt][3] + bv[nt].w, 0.f) };
                    *(bf16x4_t*)swzp<9>(h2, m * 16 + c, (w * 2 + nt) * 32 + q * 8) = hv;
                }
            }
        }
        // L4(e-1): h3 -> h4 — wD prefetched in Y(e-1)
        if (e > 0) do_l4(e - 1);
        __syncthreads();

        // ---- Y phase: issue wE(e-1), wB(e+1), wD(e) ----
        if (e > 0) {
#pragma unroll
            for (int ks = 0; ks < 2; ks++)
                wE[ks] = *(const bf16x8*)(Wep + 73728 + ((size_t)(w * 2 + ks) * 64 + lane) * 8);
        }
#pragma unroll
        for (int nt = 0; nt < 2; nt++)
#pragma unroll
            for (int ks = 0; ks < 2; ks++)
                wB[nt][ks] = *(const bf16x8*)(Wen + 16384 + ((size_t)((w * 2 + nt) * 2 + ks) * 64 + lane) * 8);
#pragma unroll
        for (int ks = 0; ks < 4; ks++)
            wD[ks] = *(const bf16x8*)(We + 65536 + ((size_t)(fg * 4 + ks) * 64 + lane) * 8);

        // L3(e): h2 -> h3 (f-tile w, all m) — wC prefetched in X(e)
        {
            const float4 bv = *(const float4*)(b3 + (size_t)e * H3D + w * 16 + q * 4);
#pragma unroll
            for (int m = 0; m < 4; m++) {
                f32x4 acc = (f32x4){0.f, 0.f, 0.f, 0.f};
#pragma unroll
                for (int ks = 0; ks < 8; ks++) {
                    bf16x8 ha = *(const bf16x8*)swzp<9>(h2, m * 16 + c, ks * 64 + q * 16);
                    acc = __builtin_amdgcn_mfma_f32_16x16x32_bf16(wC[ks], ha, acc, 0, 0, 0);
                }
                bf16x4_t hv = { (bf16_t)fmaxf(acc[0] + bv.x, 0.f),
                                (bf16_t)fmaxf(acc[1] + bv.y, 0.f),
                                (bf16_t)fmaxf(acc[2] + bv.z, 0.f),
                                (bf16_t)fmaxf(acc[3] + bv.w, 0.f) };
                *(bf16x4_t*)swzp<8>(h3, m * 16 + c, w * 32 + q * 8) = hv;
            }
        }
        // L1(e+1): sX -> h1 — wA prefetched in X(e)
        if (e < NE - 1) {
            const float4 bv = *(const float4*)(b1 + (size_t)(e + 1) * H1D + fg * 16 + q * 4);
#pragma unroll
            for (int mm = 0; mm < 2; mm++) {
                const int m = mh * 2 + mm;
                f32x4 acc = (f32x4){0.f, 0.f, 0.f, 0.f};
#pragma unroll
                for (int ks = 0; ks < 8; ks++) {
                    bf16x8 xv = *(const bf16x8*)swzp<9>(sX, m * 16 + c, ks * 64 + q * 16);
                    acc = __builtin_amdgcn_mfma_f32_16x16x32_bf16(wA[ks], xv, acc, 0, 0, 0);
                }
                bf16x4_t hv = { (bf16_t)fmaxf(acc[0] + bv.x, 0.f),
                                (bf16_t)fmaxf(acc[1] + bv.y, 0.f),
                                (bf16_t)fmaxf(acc[2] + bv.z, 0.f),
                                (bf16_t)fmaxf(acc[3] + bv.w, 0.f) };
                *(bf16x4_t*)swzp<7>(h1, m * 16 + c, fg * 32 + q * 8) = hv;
            }
        }
        // L5(e-1): h4 -> oacc — wE covered by L3+L1 above
        if (e > 0) do_l5(e - 1);
        __syncthreads();
    }

    // ---- epilogue: issue wE(31); L4(31) (wD from Y(31)); bar; L5(31) ----
#pragma unroll
    for (int ks = 0; ks < 2; ks++)
        wE[ks] = *(const bf16x8*)(Wf + (size_t)31 * 81920 + 73728 + ((size_t)(w * 2 + ks) * 64 + lane) * 8);
    do_l4(NE - 1);
    __syncthreads();
    do_l5(NE - 1);

    // ---- store: lane owns rows m*16+c, cols w*16 + q*4 .. +3 ----
#pragma unroll
    for (int m = 0; m < 4; m++)
        *(float4*)(out + (size_t)(b0 + m * 16 + c) * NOUT + w * 16 + q * 4) =
            (float4){oacc[m][0], oacc[m][1], oacc[m][2], oacc[m][3]};
}

extern "C" void kernel_launch(void* const* d_in, const int* in_sizes, int n_in,
                              void* d_out, int out_size, void* d_ws, size_t ws_size,
                              hipStream_t stream)
{
    (void)in_sizes; (void)n_in; (void)out_size; (void)ws_size;
    const float* x  = (const float*)d_in[0];
    const float* Wg = (const float*)d_in[1];
    const float* bg = (const float*)d_in[2];
    const float* W1 = (const float*)d_in[3];
    const float* b1 = (const float*)d_in[4];
    const float* W2 = (const float*)d_in[5];
    const float* b2 = (const float*)d_in[6];
    const float* W3 = (const float*)d_in[7];
    const float* b3 = (const float*)d_in[8];
    const float* W4 = (const float*)d_in[9];
    const float* b4 = (const float*)d_in[10];
    const float* W5 = (const float*)d_in[11];
    const float* b5 = (const float*)d_in[12];

    char* ws = (char*)d_ws;
    bf16_t* Wf  = (bf16_t*)(ws + OFF_WF);
    bf16_t* Wgf = (bf16_t*)(ws + OFF_WGF);
    float*  outp = (float*)d_out;

    build_frags<<<dim3(644), dim3(256), 0, stream>>>(W1, W2, W3, W4, W5, Wg, Wf, Wgf);
    moe_main<<<dim3(BB / 64), dim3(512), 0, stream>>>(x, Wf, Wgf, bg,
                                                      b1, b2, b3, b4, b5, outp);
}